// Round 11
// baseline (155.679 us; speedup 1.0000x reference)
//
#include <hip/hip_runtime.h>
#include <math.h>

#define N_    8
#define C_    512
#define HW_   1024
#define G_    32
#define CPG_  16
#define OC3_  1536
#define LOG2E 1.44269504f

typedef _Float16 f16;
typedef f16 f16x8 __attribute__((ext_vector_type(8)));
typedef f16 f16x4 __attribute__((ext_vector_type(4)));
typedef float f32x4 __attribute__((ext_vector_type(4)));

#define GLOAD_LDS16(g, l)                                                          \
    __builtin_amdgcn_global_load_lds(                                              \
        (const __attribute__((address_space(1))) unsigned int*)(const void*)(g),   \
        (__attribute__((address_space(3))) unsigned int*)(void*)(l), 16, 0, 0)

// s_waitcnt vmcnt(0) only (lgkmcnt=15, expcnt=7 -> no wait): simm16 = 0x0F70
#define WAIT_VM0() __builtin_amdgcn_s_waitcnt(0x0F70)

// ---------------- prep: GroupNorm+transpose (blocks 0..255) | weight pack (rest)
__global__ __launch_bounds__(256) void prep(const float* __restrict__ x,
                                            const float* __restrict__ gw,
                                            const float* __restrict__ gb,
                                            f16* __restrict__ XT,
                                            const float* __restrict__ qkv_w,
                                            const float* __restrict__ out_w,
                                            const float* __restrict__ qkv_b,
                                            f16* __restrict__ Wq,
                                            f16* __restrict__ Wo,
                                            float* __restrict__ qkv_bs) {
    __shared__ float red1[4], red2[4];
    __shared__ float sm, srstd;
    if (blockIdx.x >= 256) {   // ---- weight pack path ----
        const float QS = 0.125f * LOG2E;
        int idx = (blockIdx.x - 256) * 256 + threadIdx.x;
        if (idx < 786432) {
            float v = qkv_w[idx];
            if (idx < 262144) v *= QS;              // q rows (o < 512)
            Wq[idx] = (f16)v;
        } else if (idx < 786432 + 262144) {
            Wo[idx - 786432] = (f16)out_w[idx - 786432];
        } else if (idx < 786432 + 262144 + 1536) {
            int i = idx - 786432 - 262144;
            float v = qkv_b[i];
            if (i < 512) v *= QS;
            qkv_bs[i] = v;
        }
        return;
    }
    // ---- GroupNorm path ----
    int blk = blockIdx.x;
    int n = blk >> 5, g = blk & 31;
    size_t base = ((size_t)n * C_ + (size_t)g * CPG_) * HW_;
    const float4* xp4 = (const float4*)(x + base);
    float4 vals[16];
    float s1 = 0.f, s2 = 0.f;
#pragma unroll
    for (int r = 0; r < 16; r++) {
        float4 v = xp4[r * 256 + threadIdx.x];   // c_local = r, l = 4*tid..4*tid+3
        vals[r] = v;
        s1 += v.x + v.y + v.z + v.w;
        s2 += v.x * v.x + v.y * v.y + v.z * v.z + v.w * v.w;
    }
#pragma unroll
    for (int off = 32; off > 0; off >>= 1) {
        s1 += __shfl_down(s1, off, 64);
        s2 += __shfl_down(s2, off, 64);
    }
    int wave = threadIdx.x >> 6, lane = threadIdx.x & 63;
    if (lane == 0) { red1[wave] = s1; red2[wave] = s2; }
    __syncthreads();
    if (threadIdx.x == 0) {
        float t1 = red1[0] + red1[1] + red1[2] + red1[3];
        float t2 = red2[0] + red2[1] + red2[2] + red2[3];
        float mean = t1 * (1.f / 16384.f);
        float var  = t2 * (1.f / 16384.f) - mean * mean;
        sm = mean;
        srstd = rsqrtf(var + 1e-5f);
    }
    __syncthreads();
    float mean = sm, rstd = srstd;
    float av[16], bbv[16];
#pragma unroll
    for (int r = 0; r < 16; r++) {
        int c = g * CPG_ + r;
        av[r] = gw[c] * rstd;
        bbv[r] = gb[c] - mean * av[r];
    }
    f16x8 lo[4], hi[4];
#pragma unroll
    for (int r = 0; r < 16; r++) {
        float4 v = vals[r];
        float a = av[r], bb = bbv[r];
        f16 e0 = (f16)(v.x * a + bb), e1 = (f16)(v.y * a + bb);
        f16 e2 = (f16)(v.z * a + bb), e3 = (f16)(v.w * a + bb);
        if (r < 8) { lo[0][r] = e0; lo[1][r] = e1; lo[2][r] = e2; lo[3][r] = e3; }
        else { hi[0][r - 8] = e0; hi[1][r - 8] = e1; hi[2][r - 8] = e2; hi[3][r - 8] = e3; }
    }
    f16* xt = XT + ((size_t)n * HW_ + (size_t)threadIdx.x * 4) * C_ + g * CPG_;
#pragma unroll
    for (int comp = 0; comp < 4; comp++) {
        *(f16x8*)&xt[(size_t)comp * C_]     = lo[comp];
        *(f16x8*)&xt[(size_t)comp * C_ + 8] = hi[comp];
    }
}

// ---------------- fp16 MFMA GEMM, m97-style DMA staging, XCD-swizzled grid -----
// Y[o][l] = sum_c A[o][c] * B[n][l][c] + bias. Tile 128x128, BK=64.
// flat grid: n = flat & 7 (same n -> same XCD), l_t = (flat>>3)&7, o_t = flat>>6.
template <bool FINAL>
__global__ __launch_bounds__(256, 4) void gemm_f16(const f16* __restrict__ A,
                                                   const f16* __restrict__ B,
                                                   const float* __restrict__ bias,
                                                   void* __restrict__ Yq,
                                                   f16* __restrict__ Yv) {
    __shared__ __align__(16) unsigned char smem[34816];
    f16* As = (f16*)smem;              // [128][64], xor-swizzled 16B segs
    f16* Bs = (f16*)(smem + 16384);
    int tid = threadIdx.x, lane = tid & 63, w = tid >> 6;
    int m = lane & 15, quad = lane >> 4;
    int ow0 = (w & 1) * 64, lw0 = (w >> 1) * 64;
    int flat = blockIdx.x;
    int n = flat & 7, rest = flat >> 3;
    int l0 = (rest & 7) * 128, o0 = (rest >> 3) * 128;
    const f16* Bn = B + ((size_t)n * HW_ + l0) * 512;

    int rowT[4], sgT[4];
#pragma unroll
    for (int t = 0; t < 4; t++) {
        int q = (w * 4 + t) * 64 + lane;
        int row = q >> 3, seg = q & 7;
        rowT[t] = row;
        sgT[t] = seg ^ (row & 7);
    }

    f32x4 acc[4][4];
#pragma unroll
    for (int i = 0; i < 4; i++)
#pragma unroll
        for (int j = 0; j < 4; j++)
#pragma unroll
            for (int r = 0; r < 4; r++) acc[i][j][r] = 0.f;

    for (int c0 = 0; c0 < 512; c0 += 64) {
        __syncthreads();                    // prev compute done reading LDS
#pragma unroll
        for (int t = 0; t < 4; t++) {       // DMA this slab straight to LDS
            GLOAD_LDS16(A + (size_t)(o0 + rowT[t]) * 512 + c0 + sgT[t] * 8,
                        As + (size_t)(w * 4 + t) * 512);
            GLOAD_LDS16(Bn + (size_t)rowT[t] * 512 + c0 + sgT[t] * 8,
                        Bs + (size_t)(w * 4 + t) * 512);
        }
        WAIT_VM0();                         // own DMA landed
        __syncthreads();                    // everyone's DMA landed
#pragma unroll
        for (int ks = 0; ks < 2; ks++) {
            f16x8 af[4], bf[4];
#pragma unroll
            for (int ib = 0; ib < 4; ib++) {
                int row = ow0 + ib * 16 + m;
                int seg = (ks * 4 + quad) ^ (row & 7);
                af[ib] = *(const f16x8*)&As[row * 64 + seg * 8];
            }
#pragma unroll
            for (int jb = 0; jb < 4; jb++) {
                int row = lw0 + jb * 16 + m;
                int seg = (ks * 4 + quad) ^ (row & 7);
                bf[jb] = *(const f16x8*)&Bs[row * 64 + seg * 8];
            }
#pragma unroll
            for (int ib = 0; ib < 4; ib++)
#pragma unroll
                for (int jb = 0; jb < 4; jb++)
                    acc[ib][jb] = __builtin_amdgcn_mfma_f32_16x16x32_f16(
                        af[ib], bf[jb], acc[ib][jb], 0, 0, 0);
        }
    }

    float bv[4][4];
#pragma unroll
    for (int ib = 0; ib < 4; ib++)
#pragma unroll
        for (int r = 0; r < 4; r++)
            bv[ib][r] = bias[o0 + ow0 + ib * 16 + quad * 4 + r];

    if (FINAL) {
        float* on = (float*)Yq + (size_t)n * C_ * HW_;
#pragma unroll
        for (int ib = 0; ib < 4; ib++)
#pragma unroll
            for (int jb = 0; jb < 4; jb++)
#pragma unroll
                for (int r = 0; r < 4; r++)
                    on[(size_t)(o0 + ow0 + ib * 16 + quad * 4 + r) * HW_ +
                       l0 + lw0 + jb * 16 + m] = acc[ib][jb][r] + bv[ib][r];
    } else if (o0 >= 1024) {
        f16* vn = Yv + (size_t)n * C_ * HW_;
#pragma unroll
        for (int ib = 0; ib < 4; ib++)
#pragma unroll
            for (int jb = 0; jb < 4; jb++)
#pragma unroll
                for (int r = 0; r < 4; r++)
                    vn[(size_t)(o0 - 1024 + ow0 + ib * 16 + quad * 4 + r) * HW_ +
                       l0 + lw0 + jb * 16 + m] = (f16)(acc[ib][jb][r] + bv[ib][r]);
    } else {
        __syncthreads();                 // staging reads done; reuse smem
        f16* T = (f16*)smem;             // [128][136]
#pragma unroll
        for (int ib = 0; ib < 4; ib++)
#pragma unroll
            for (int jb = 0; jb < 4; jb++) {
                f16x4 h;
#pragma unroll
                for (int r = 0; r < 4; r++) h[r] = (f16)(acc[ib][jb][r] + bv[ib][r]);
                int l = lw0 + jb * 16 + m;
                int oo = ow0 + ib * 16 + quad * 4;
                *(f16x4*)&T[l * 136 + oo] = h;
            }
        __syncthreads();
        f16* qn = (f16*)Yq + (size_t)n * HW_ * 1024;
#pragma unroll
        for (int rep = 0; rep < 8; rep++) {
            int idx = rep * 256 + tid;
            int l = idx >> 4, seg = idx & 15;
            f16x8 v = *(const f16x8*)&T[l * 136 + seg * 8];
            *(f16x8*)&qn[(size_t)(l0 + l) * 1024 + o0 + seg * 8] = v;
        }
    }
}

// ---------------- Flash attention fp16 MFMA, 128-row i-tiles ----------------
// S^T form (mfma(K,Q)); DMA-dbuf K/V; each wave owns TWO 16-row strips so each
// barrier covers 32 MFMA instead of 16. grid 512 flat, XCD-swizzled.
__global__ __launch_bounds__(256, 4) void attn_f16(const f16* __restrict__ qkvT,
                                                   const f16* __restrict__ vbuf,
                                                   f16* __restrict__ w2T) {
    __shared__ __align__(16) unsigned char smem[49152];
    f16* Kb0  = (f16*)smem;                 // two 8 KB K buffers at 0, 8192
    f16* Vb0  = (f16*)(smem + 16384);       // two 8 KB V buffers at 16384, 24576
    f16* Ps   = (f16*)(smem + 32768);       // 8 strips x [16 i][64 j] = 16 KB
    f16* LDSo = (f16*)smem;                 // epilogue alias of K/V area (16 KB)

    int tid = threadIdx.x;
    int lane = tid & 63, wave = tid >> 6;
    int m = lane & 15, quad = lane >> 4;
    // XCD swizzle: flat = (itile*8 + bh_hi)*8 + xcd ; bh = bh_hi*8 + xcd
    int flat = blockIdx.x;                  // 512 blocks
    int xcd = flat & 7, slot = flat >> 3;
    int itile = slot >> 3, bh = (slot & 7) * 8 + xcd;
    int n = bh >> 3, head = bh & 7;
    int i0 = itile * 128;
    const f16* qb = qkvT + (size_t)n * HW_ * 1024 + head * 64;
    const f16* kb = qb + 512;
    const f16* vb = vbuf + (size_t)n * C_ * HW_ + (size_t)head * 64 * HW_;

    // Q fragments for both strips (rows i0 + wave*32 + s*16 + m)
    f16x8 aq[2][2];
#pragma unroll
    for (int s = 0; s < 2; s++) {
        const f16* qr = qb + (size_t)(i0 + wave * 32 + s * 16 + m) * 1024;
        aq[s][0] = *(const f16x8*)&qr[quad * 8];
        aq[s][1] = *(const f16x8*)&qr[32 + quad * 8];
    }

    // stage tile 0 -> buffer 0 (async)
#pragma unroll
    for (int it = 0; it < 2; it++) {
        int chunk = it * 256 + tid;
        int row = chunk >> 3, seg = chunk & 7;
        int segg = seg ^ (row & 7);
        GLOAD_LDS16(kb + (size_t)row * 1024 + segg * 8,
                    Kb0 + ((size_t)it * 256 + wave * 64) * 8);
        GLOAD_LDS16(vb + (size_t)row * HW_ + segg * 8,
                    Vb0 + ((size_t)it * 256 + wave * 64) * 8);
    }

    f32x4 oacc[2][4];
#pragma unroll
    for (int s = 0; s < 2; s++)
#pragma unroll
        for (int cb = 0; cb < 4; cb++)
#pragma unroll
            for (int r = 0; r < 4; r++) oacc[s][cb][r] = 0.f;
    float lsum[2] = {0.f, 0.f};

    for (int jt = 0; jt < 16; jt++) {
        int p = jt & 1;
        const f16* Kp = Kb0 + p * 4096;
        const f16* Vp = Vb0 + p * 4096;
        WAIT_VM0();        // drain own LDS-DMA before the barrier
        __syncthreads();   // all waves aligned => buffer p fully written
        if (jt < 15) {     // prefetch tile jt+1 into the other buffer
            int j0n = (jt + 1) * 64;
            f16* Kn = Kb0 + (1 - p) * 4096;
            f16* Vn = Vb0 + (1 - p) * 4096;
#pragma unroll
            for (int it = 0; it < 2; it++) {
                int chunk = it * 256 + tid;
                int row = chunk >> 3, seg = chunk & 7;
                int segg = seg ^ (row & 7);
                GLOAD_LDS16(kb + (size_t)(j0n + row) * 1024 + segg * 8,
                            Kn + ((size_t)it * 256 + wave * 64) * 8);
                GLOAD_LDS16(vb + (size_t)row * HW_ + j0n + segg * 8,
                            Vn + ((size_t)it * 256 + wave * 64) * 8);
            }
        }

        // preload K fragments once (shared by both strips)
        f16x8 kf[8];
#pragma unroll
        for (int jb = 0; jb < 4; jb++) {
            int row = jb * 16 + m;
            kf[jb]     = *(const f16x8*)&Kp[row * 64 + ((quad ^ (row & 7)) * 8)];
            kf[4 + jb] = *(const f16x8*)&Kp[row * 64 + (((4 + quad) ^ (row & 7)) * 8)];
        }

#pragma unroll
        for (int s = 0; s < 2; s++) {
            f16* PsW = Ps + (size_t)(wave * 2 + s) * 1024;   // strip-private P
            // S^T = K Q^T : lane holds S[i][j = jb*16 + quad*4 + r]
            f32x4 sacc[4];
#pragma unroll
            for (int jb = 0; jb < 4; jb++)
#pragma unroll
                for (int r = 0; r < 4; r++) sacc[jb][r] = 0.f;
#pragma unroll
            for (int jb = 0; jb < 4; jb++)
                sacc[jb] = __builtin_amdgcn_mfma_f32_16x16x32_f16(kf[jb], aq[s][0],
                                                                  sacc[jb], 0, 0, 0);
#pragma unroll
            for (int jb = 0; jb < 4; jb++)
                sacc[jb] = __builtin_amdgcn_mfma_f32_16x16x32_f16(kf[4 + jb], aq[s][1],
                                                                  sacc[jb], 0, 0, 0);

            // max-free softmax: p = 2^s (log2 scale folded into Wq); packed stores
#pragma unroll
            for (int jb = 0; jb < 4; jb++) {
                f16x4 h;
#pragma unroll
                for (int r = 0; r < 4; r++) {
                    float pv = exp2f(sacc[jb][r]);
                    h[r] = (f16)pv;
                    lsum[s] += pv;
                }
                int seg = jb * 4 + quad;
                *(f16x4*)&PsW[m * 64 + ((seg ^ (m & 7)) * 4)] = h;
            }
            // no barrier: strip P produced & consumed by this wave only

            // O += P V
#pragma unroll
            for (int ks = 0; ks < 2; ks++) {
                int s0 = ks * 8 + quad * 2;
                f16x4 apl = *(const f16x4*)&PsW[m * 64 + ((s0 ^ (m & 7)) * 4)];
                f16x4 aph = *(const f16x4*)&PsW[m * 64 + (((s0 + 1) ^ (m & 7)) * 4)];
                f16x8 ap = {apl[0], apl[1], apl[2], apl[3],
                            aph[0], aph[1], aph[2], aph[3]};
#pragma unroll
                for (int cb = 0; cb < 4; cb++) {
                    int vrow = cb * 16 + m;
                    f16x8 bvv = *(const f16x8*)&Vp[vrow * 64 +
                                                   (((ks * 4 + quad) ^ (vrow & 7)) * 8)];
                    oacc[s][cb] = __builtin_amdgcn_mfma_f32_16x16x32_f16(
                        ap, bvv, oacc[s][cb], 0, 0, 0);
                }
            }
        }
    }

    // row sums per strip; lane's partial is for row (wave*32 + s*16 + m)
    float linv[2][4];
#pragma unroll
    for (int s = 0; s < 2; s++) {
        float ls = lsum[s];
        ls += __shfl_xor(ls, 16, 64);
        ls += __shfl_xor(ls, 32, 64);
#pragma unroll
        for (int r = 0; r < 4; r++)
            linv[s][r] = 1.f / __shfl(ls, quad * 4 + r, 64);
    }
    WAIT_VM0();
    __syncthreads();   // everyone done with K/V buffers before aliasing
    // torch-reshape epilogue: local row li = wave*32+s*16+quad*4+r ->
    // ch-slot = li>>4 = wave*2+s ; s-coord = (li&15)*64 + cb*16 + m
#pragma unroll
    for (int s = 0; s < 2; s++)
#pragma unroll
        for (int cb = 0; cb < 4; cb++)
#pragma unroll
            for (int r = 0; r < 4; r++) {
                int sc = (quad * 4 + r) * 64 + cb * 16 + m;
                LDSo[sc * 8 + wave * 2 + s] = (f16)(oacc[s][cb][r] * linv[s][r]);
            }
    __syncthreads();
    f16* w2n = w2T + (size_t)n * HW_ * 512;
    int chbase = head * 64 + (i0 >> 4);     // multiple of 8 -> 16B aligned
#pragma unroll
    for (int it = 0; it < 4; it++) {
        int sc = it * 256 + tid;
        *(f16x8*)&w2n[(size_t)sc * 512 + chbase] = *(const f16x8*)&LDSo[sc * 8];
    }
}

extern "C" void kernel_launch(void* const* d_in, const int* in_sizes, int n_in,
                              void* d_out, int out_size, void* d_ws, size_t ws_size,
                              hipStream_t stream) {
    (void)in_sizes; (void)n_in; (void)out_size; (void)ws_size;
    const float* x     = (const float*)d_in[0];
    const float* gw    = (const float*)d_in[1];
    const float* gb    = (const float*)d_in[2];
    const float* qkv_w = (const float*)d_in[3];
    const float* qkv_b = (const float*)d_in[4];
    const float* out_w = (const float*)d_in[5];
    const float* out_b = (const float*)d_in[6];
    float* out = (float*)d_out;
    char* ws = (char*)d_ws;

    const size_t MB = 1024 * 1024;
    f16*   qkvT   = (f16*)ws;                       // [8][1024][1024] q|k  (16 MB)
    f16*   XT     = (f16*)(ws + 16 * MB);           // [8][1024][512]       (8 MB)
    f16*   vbuf   = (f16*)(ws + 24 * MB);           // [8][512][1024]       (8 MB)
    f16*   w2T    = (f16*)(ws + 32 * MB);           // [8][1024][512]       (8 MB)
    f16*   Wq     = (f16*)(ws + 40 * MB);           // [1536][512]          (1.5 MB)
    f16*   Wo     = (f16*)(ws + 42 * MB);           // [512][512]           (0.5 MB)
    float* qkv_bs = (float*)(ws + 43 * MB);         // [1536]

    prep<<<dim3(256 + 4103), 256, 0, stream>>>(x, gw, gb, XT,
                                               qkv_w, out_w, qkv_b, Wq, Wo, qkv_bs);
    gemm_f16<false><<<dim3(768), 256, 0, stream>>>(Wq, XT, qkv_bs, (void*)qkvT, vbuf);
    attn_f16<<<dim3(512), 256, 0, stream>>>(qkvT, vbuf, w2T);
    gemm_f16<true><<<dim3(256), 256, 0, stream>>>(Wo, w2T, out_b, (void*)out, nullptr);
}

// Round 12
// 150.114 us; speedup vs baseline: 1.0371x; 1.0371x over previous
//
#include <hip/hip_runtime.h>
#include <math.h>

#define N_    8
#define C_    512
#define HW_   1024
#define G_    32
#define CPG_  16
#define OC3_  1536
#define LOG2E 1.44269504f

typedef _Float16 f16;
typedef f16 f16x8 __attribute__((ext_vector_type(8)));
typedef f16 f16x4 __attribute__((ext_vector_type(4)));
typedef float f32x4 __attribute__((ext_vector_type(4)));

#define GLOAD_LDS16(g, l)                                                          \
    __builtin_amdgcn_global_load_lds(                                              \
        (const __attribute__((address_space(1))) unsigned int*)(const void*)(g),   \
        (__attribute__((address_space(3))) unsigned int*)(void*)(l), 16, 0, 0)

// s_waitcnt vmcnt(0) only (lgkmcnt=15, expcnt=7 -> no wait): simm16 = 0x0F70
#define WAIT_VM0() __builtin_amdgcn_s_waitcnt(0x0F70)

// ---------------- prep: GroupNorm+transpose (blocks 0..255) | weight pack (rest)
// XT is BLOCKED: [n][cb=c/16][l][16] so prep writes are fully coalesced
// (each thread writes 128 B contiguous).
__global__ __launch_bounds__(256) void prep(const float* __restrict__ x,
                                            const float* __restrict__ gw,
                                            const float* __restrict__ gb,
                                            f16* __restrict__ XT,
                                            const float* __restrict__ qkv_w,
                                            const float* __restrict__ out_w,
                                            const float* __restrict__ qkv_b,
                                            f16* __restrict__ Wq,
                                            f16* __restrict__ Wo,
                                            float* __restrict__ qkv_bs) {
    __shared__ float red1[4], red2[4];
    __shared__ float sm, srstd;
    if (blockIdx.x >= 256) {   // ---- weight pack path ----
        const float QS = 0.125f * LOG2E;
        int idx = (blockIdx.x - 256) * 256 + threadIdx.x;
        if (idx < 786432) {
            float v = qkv_w[idx];
            if (idx < 262144) v *= QS;              // q rows (o < 512)
            Wq[idx] = (f16)v;
        } else if (idx < 786432 + 262144) {
            Wo[idx - 786432] = (f16)out_w[idx - 786432];
        } else if (idx < 786432 + 262144 + 1536) {
            int i = idx - 786432 - 262144;
            float v = qkv_b[i];
            if (i < 512) v *= QS;
            qkv_bs[i] = v;
        }
        return;
    }
    // ---- GroupNorm path ----
    int blk = blockIdx.x;
    int n = blk >> 5, g = blk & 31;
    size_t base = ((size_t)n * C_ + (size_t)g * CPG_) * HW_;
    const float4* xp4 = (const float4*)(x + base);
    float4 vals[16];
    float s1 = 0.f, s2 = 0.f;
#pragma unroll
    for (int r = 0; r < 16; r++) {
        float4 v = xp4[r * 256 + threadIdx.x];   // c_local = r, l = 4*tid..4*tid+3
        vals[r] = v;
        s1 += v.x + v.y + v.z + v.w;
        s2 += v.x * v.x + v.y * v.y + v.z * v.z + v.w * v.w;
    }
#pragma unroll
    for (int off = 32; off > 0; off >>= 1) {
        s1 += __shfl_down(s1, off, 64);
        s2 += __shfl_down(s2, off, 64);
    }
    int wave = threadIdx.x >> 6, lane = threadIdx.x & 63;
    if (lane == 0) { red1[wave] = s1; red2[wave] = s2; }
    __syncthreads();
    if (threadIdx.x == 0) {
        float t1 = red1[0] + red1[1] + red1[2] + red1[3];
        float t2 = red2[0] + red2[1] + red2[2] + red2[3];
        float mean = t1 * (1.f / 16384.f);
        float var  = t2 * (1.f / 16384.f) - mean * mean;
        sm = mean;
        srstd = rsqrtf(var + 1e-5f);
    }
    __syncthreads();
    float mean = sm, rstd = srstd;
    float av[16], bbv[16];
#pragma unroll
    for (int r = 0; r < 16; r++) {
        int c = g * CPG_ + r;
        av[r] = gw[c] * rstd;
        bbv[r] = gb[c] - mean * av[r];
    }
    f16x8 lo[4], hi[4];
#pragma unroll
    for (int r = 0; r < 16; r++) {
        float4 v = vals[r];
        float a = av[r], bb = bbv[r];
        f16 e0 = (f16)(v.x * a + bb), e1 = (f16)(v.y * a + bb);
        f16 e2 = (f16)(v.z * a + bb), e3 = (f16)(v.w * a + bb);
        if (r < 8) { lo[0][r] = e0; lo[1][r] = e1; lo[2][r] = e2; lo[3][r] = e3; }
        else { hi[0][r - 8] = e0; hi[1][r - 8] = e1; hi[2][r - 8] = e2; hi[3][r - 8] = e3; }
    }
    // blocked store: [n][g][l][16], each thread 4 l's x 32 B contiguous = 128 B
    f16* xt = XT + (size_t)n * C_ * HW_ + ((size_t)g * HW_ + threadIdx.x * 4) * 16;
#pragma unroll
    for (int comp = 0; comp < 4; comp++) {
        *(f16x8*)&xt[comp * 16]     = lo[comp];
        *(f16x8*)&xt[comp * 16 + 8] = hi[comp];
    }
}

// ---------------- fp16 MFMA GEMM, m97-style DMA staging, XCD-swizzled grid -----
// Y[o][l] = sum_c A[o][c] * B[...] + bias. Tile 128x128, BK=64.
// FINAL=false: B is blocked XT [n][cb][l][16]; FINAL=true: B is w2T [n][l][512].
template <bool FINAL>
__global__ __launch_bounds__(256, 4) void gemm_f16(const f16* __restrict__ A,
                                                   const f16* __restrict__ B,
                                                   const float* __restrict__ bias,
                                                   void* __restrict__ Yq,
                                                   f16* __restrict__ Yv) {
    __shared__ __align__(16) unsigned char smem[34816];
    f16* As = (f16*)smem;              // [128][64], xor-swizzled 16B segs
    f16* Bs = (f16*)(smem + 16384);
    int tid = threadIdx.x, lane = tid & 63, w = tid >> 6;
    int m = lane & 15, quad = lane >> 4;
    int ow0 = (w & 1) * 64, lw0 = (w >> 1) * 64;
    int flat = blockIdx.x;
    int n = flat & 7, rest = flat >> 3;
    int l0 = (rest & 7) * 128, o0 = (rest >> 3) * 128;
    const f16* Bn = B + (size_t)n * C_ * HW_;   // 512*1024 elements either layout

    int rowT[4], sgT[4];
#pragma unroll
    for (int t = 0; t < 4; t++) {
        int q = (w * 4 + t) * 64 + lane;
        int row = q >> 3, seg = q & 7;
        rowT[t] = row;
        sgT[t] = seg ^ (row & 7);
    }

    f32x4 acc[4][4];
#pragma unroll
    for (int i = 0; i < 4; i++)
#pragma unroll
        for (int j = 0; j < 4; j++)
#pragma unroll
            for (int r = 0; r < 4; r++) acc[i][j][r] = 0.f;

    for (int c0 = 0; c0 < 512; c0 += 64) {
        __syncthreads();                    // prev compute done reading LDS
#pragma unroll
        for (int t = 0; t < 4; t++) {       // DMA this slab straight to LDS
            GLOAD_LDS16(A + (size_t)(o0 + rowT[t]) * 512 + c0 + sgT[t] * 8,
                        As + (size_t)(w * 4 + t) * 512);
            size_t baddr;
            if (FINAL) {
                baddr = (size_t)(l0 + rowT[t]) * 512 + c0 + sgT[t] * 8;
            } else {
                int c = c0 + sgT[t] * 8;
                baddr = ((size_t)(c >> 4) * HW_ + (l0 + rowT[t])) * 16 + (c & 15);
            }
            GLOAD_LDS16(Bn + baddr, Bs + (size_t)(w * 4 + t) * 512);
        }
        WAIT_VM0();                         // own DMA landed
        __syncthreads();                    // everyone's DMA landed
#pragma unroll
        for (int ks = 0; ks < 2; ks++) {
            f16x8 af[4], bf[4];
#pragma unroll
            for (int ib = 0; ib < 4; ib++) {
                int row = ow0 + ib * 16 + m;
                int seg = (ks * 4 + quad) ^ (row & 7);
                af[ib] = *(const f16x8*)&As[row * 64 + seg * 8];
            }
#pragma unroll
            for (int jb = 0; jb < 4; jb++) {
                int row = lw0 + jb * 16 + m;
                int seg = (ks * 4 + quad) ^ (row & 7);
                bf[jb] = *(const f16x8*)&Bs[row * 64 + seg * 8];
            }
#pragma unroll
            for (int ib = 0; ib < 4; ib++)
#pragma unroll
                for (int jb = 0; jb < 4; jb++)
                    acc[ib][jb] = __builtin_amdgcn_mfma_f32_16x16x32_f16(
                        af[ib], bf[jb], acc[ib][jb], 0, 0, 0);
        }
    }

    float bv[4][4];
#pragma unroll
    for (int ib = 0; ib < 4; ib++)
#pragma unroll
        for (int r = 0; r < 4; r++)
            bv[ib][r] = bias[o0 + ow0 + ib * 16 + quad * 4 + r];

    if (FINAL) {
        float* on = (float*)Yq + (size_t)n * C_ * HW_;
#pragma unroll
        for (int ib = 0; ib < 4; ib++)
#pragma unroll
            for (int jb = 0; jb < 4; jb++)
#pragma unroll
                for (int r = 0; r < 4; r++)
                    on[(size_t)(o0 + ow0 + ib * 16 + quad * 4 + r) * HW_ +
                       l0 + lw0 + jb * 16 + m] = acc[ib][jb][r] + bv[ib][r];
    } else if (o0 >= 1024) {
        f16* vn = Yv + (size_t)n * C_ * HW_;
#pragma unroll
        for (int ib = 0; ib < 4; ib++)
#pragma unroll
            for (int jb = 0; jb < 4; jb++)
#pragma unroll
                for (int r = 0; r < 4; r++)
                    vn[(size_t)(o0 - 1024 + ow0 + ib * 16 + quad * 4 + r) * HW_ +
                       l0 + lw0 + jb * 16 + m] = (f16)(acc[ib][jb][r] + bv[ib][r]);
    } else {
        __syncthreads();                 // staging reads done; reuse smem
        f16* T = (f16*)smem;             // [128][136]
#pragma unroll
        for (int ib = 0; ib < 4; ib++)
#pragma unroll
            for (int jb = 0; jb < 4; jb++) {
                f16x4 h;
#pragma unroll
                for (int r = 0; r < 4; r++) h[r] = (f16)(acc[ib][jb][r] + bv[ib][r]);
                int l = lw0 + jb * 16 + m;
                int oo = ow0 + ib * 16 + quad * 4;
                *(f16x4*)&T[l * 136 + oo] = h;
            }
        __syncthreads();
        f16* qn = (f16*)Yq + (size_t)n * HW_ * 1024;
#pragma unroll
        for (int rep = 0; rep < 8; rep++) {
            int idx = rep * 256 + tid;
            int l = idx >> 4, seg = idx & 15;
            f16x8 v = *(const f16x8*)&T[l * 136 + seg * 8];
            *(f16x8*)&qn[(size_t)(l0 + l) * 1024 + o0 + seg * 8] = v;
        }
    }
}

// ---------------- Flash attention fp16 MFMA, 128-row i-tiles ----------------
// S^T form (mfma(K,Q)); DMA-dbuf K/V; two 16-row strips per wave. K AND V
// fragments hoisted out of the strip loop (strip-invariant) -> DS traffic
// per iter: K 8KB + V 8KB + P 8KB per wave. grid 512 flat, XCD-swizzled.
__global__ __launch_bounds__(256, 3) void attn_f16(const f16* __restrict__ qkvT,
                                                   const f16* __restrict__ vbuf,
                                                   f16* __restrict__ w2T) {
    __shared__ __align__(16) unsigned char smem[49152];
    f16* Kb0  = (f16*)smem;                 // two 8 KB K buffers at 0, 8192
    f16* Vb0  = (f16*)(smem + 16384);       // two 8 KB V buffers at 16384, 24576
    f16* Ps   = (f16*)(smem + 32768);       // 8 strips x [16 i][64 j] = 16 KB
    f16* LDSo = (f16*)smem;                 // epilogue alias of K/V area (16 KB)

    int tid = threadIdx.x;
    int lane = tid & 63, wave = tid >> 6;
    int m = lane & 15, quad = lane >> 4;
    // XCD swizzle: flat = (itile*8 + bh_hi)*8 + xcd ; bh = bh_hi*8 + xcd
    int flat = blockIdx.x;                  // 512 blocks
    int xcd = flat & 7, slot = flat >> 3;
    int itile = slot >> 3, bh = (slot & 7) * 8 + xcd;
    int n = bh >> 3, head = bh & 7;
    int i0 = itile * 128;
    const f16* qb = qkvT + (size_t)n * HW_ * 1024 + head * 64;
    const f16* kb = qb + 512;
    const f16* vb = vbuf + (size_t)n * C_ * HW_ + (size_t)head * 64 * HW_;

    // Q fragments for both strips (rows i0 + wave*32 + s*16 + m)
    f16x8 aq[2][2];
#pragma unroll
    for (int s = 0; s < 2; s++) {
        const f16* qr = qb + (size_t)(i0 + wave * 32 + s * 16 + m) * 1024;
        aq[s][0] = *(const f16x8*)&qr[quad * 8];
        aq[s][1] = *(const f16x8*)&qr[32 + quad * 8];
    }

    // stage tile 0 -> buffer 0 (async)
#pragma unroll
    for (int it = 0; it < 2; it++) {
        int chunk = it * 256 + tid;
        int row = chunk >> 3, seg = chunk & 7;
        int segg = seg ^ (row & 7);
        GLOAD_LDS16(kb + (size_t)row * 1024 + segg * 8,
                    Kb0 + ((size_t)it * 256 + wave * 64) * 8);
        GLOAD_LDS16(vb + (size_t)row * HW_ + segg * 8,
                    Vb0 + ((size_t)it * 256 + wave * 64) * 8);
    }

    f32x4 oacc[2][4];
#pragma unroll
    for (int s = 0; s < 2; s++)
#pragma unroll
        for (int cb = 0; cb < 4; cb++)
#pragma unroll
            for (int r = 0; r < 4; r++) oacc[s][cb][r] = 0.f;
    float lsum[2] = {0.f, 0.f};

    for (int jt = 0; jt < 16; jt++) {
        int p = jt & 1;
        const f16* Kp = Kb0 + p * 4096;
        const f16* Vp = Vb0 + p * 4096;
        WAIT_VM0();        // drain own LDS-DMA before the barrier
        __syncthreads();   // all waves aligned => buffer p fully written
        if (jt < 15) {     // prefetch tile jt+1 into the other buffer
            int j0n = (jt + 1) * 64;
            f16* Kn = Kb0 + (1 - p) * 4096;
            f16* Vn = Vb0 + (1 - p) * 4096;
#pragma unroll
            for (int it = 0; it < 2; it++) {
                int chunk = it * 256 + tid;
                int row = chunk >> 3, seg = chunk & 7;
                int segg = seg ^ (row & 7);
                GLOAD_LDS16(kb + (size_t)(j0n + row) * 1024 + segg * 8,
                            Kn + ((size_t)it * 256 + wave * 64) * 8);
                GLOAD_LDS16(vb + (size_t)row * HW_ + j0n + segg * 8,
                            Vn + ((size_t)it * 256 + wave * 64) * 8);
            }
        }

        // preload K and V fragments once (shared by both strips)
        f16x8 kf[8], vf[8];
#pragma unroll
        for (int jb = 0; jb < 4; jb++) {
            int row = jb * 16 + m;
            kf[jb]     = *(const f16x8*)&Kp[row * 64 + ((quad ^ (row & 7)) * 8)];
            kf[4 + jb] = *(const f16x8*)&Kp[row * 64 + (((4 + quad) ^ (row & 7)) * 8)];
            vf[jb]     = *(const f16x8*)&Vp[row * 64 + ((quad ^ (row & 7)) * 8)];
            vf[4 + jb] = *(const f16x8*)&Vp[row * 64 + (((4 + quad) ^ (row & 7)) * 8)];
        }

#pragma unroll
        for (int s = 0; s < 2; s++) {
            f16* PsW = Ps + (size_t)(wave * 2 + s) * 1024;   // strip-private P
            // S^T = K Q^T : lane holds S[i=m][j = jb*16 + quad*4 + r]
            f32x4 sacc[4];
#pragma unroll
            for (int jb = 0; jb < 4; jb++)
#pragma unroll
                for (int r = 0; r < 4; r++) sacc[jb][r] = 0.f;
#pragma unroll
            for (int jb = 0; jb < 4; jb++)
                sacc[jb] = __builtin_amdgcn_mfma_f32_16x16x32_f16(kf[jb], aq[s][0],
                                                                  sacc[jb], 0, 0, 0);
#pragma unroll
            for (int jb = 0; jb < 4; jb++)
                sacc[jb] = __builtin_amdgcn_mfma_f32_16x16x32_f16(kf[4 + jb], aq[s][1],
                                                                  sacc[jb], 0, 0, 0);

            // max-free softmax: p = 2^s (log2 scale folded into Wq); packed stores
#pragma unroll
            for (int jb = 0; jb < 4; jb++) {
                f16x4 h;
#pragma unroll
                for (int r = 0; r < 4; r++) {
                    float pv = exp2f(sacc[jb][r]);
                    h[r] = (f16)pv;
                    lsum[s] += pv;
                }
                int seg = jb * 4 + quad;
                *(f16x4*)&PsW[m * 64 + ((seg ^ (m & 7)) * 4)] = h;
            }
            // no barrier: strip P produced & consumed by this wave only

            // O += P V
#pragma unroll
            for (int ks = 0; ks < 2; ks++) {
                int s0 = ks * 8 + quad * 2;
                f16x4 apl = *(const f16x4*)&PsW[m * 64 + ((s0 ^ (m & 7)) * 4)];
                f16x4 aph = *(const f16x4*)&PsW[m * 64 + (((s0 + 1) ^ (m & 7)) * 4)];
                f16x8 ap = {apl[0], apl[1], apl[2], apl[3],
                            aph[0], aph[1], aph[2], aph[3]};
#pragma unroll
                for (int cb = 0; cb < 4; cb++)
                    oacc[s][cb] = __builtin_amdgcn_mfma_f32_16x16x32_f16(
                        ap, vf[ks * 4 + cb], oacc[s][cb], 0, 0, 0);
            }
        }
    }

    // row sums per strip; lane's partial is for row (wave*32 + s*16 + m)
    float linv[2][4];
#pragma unroll
    for (int s = 0; s < 2; s++) {
        float ls = lsum[s];
        ls += __shfl_xor(ls, 16, 64);
        ls += __shfl_xor(ls, 32, 64);
#pragma unroll
        for (int r = 0; r < 4; r++)
            linv[s][r] = 1.f / __shfl(ls, quad * 4 + r, 64);
    }
    WAIT_VM0();
    __syncthreads();   // everyone done with K/V buffers before aliasing
    // torch-reshape epilogue: local row li = wave*32+s*16+quad*4+r ->
    // ch-slot = li>>4 = wave*2+s ; s-coord = (li&15)*64 + cb*16 + m
#pragma unroll
    for (int s = 0; s < 2; s++)
#pragma unroll
        for (int cb = 0; cb < 4; cb++)
#pragma unroll
            for (int r = 0; r < 4; r++) {
                int sc = (quad * 4 + r) * 64 + cb * 16 + m;
                LDSo[sc * 8 + wave * 2 + s] = (f16)(oacc[s][cb][r] * linv[s][r]);
            }
    __syncthreads();
    f16* w2n = w2T + (size_t)n * HW_ * 512;
    int chbase = head * 64 + (i0 >> 4);     // multiple of 8 -> 16B aligned
#pragma unroll
    for (int it = 0; it < 4; it++) {
        int sc = it * 256 + tid;
        *(f16x8*)&w2n[(size_t)sc * 512 + chbase] = *(const f16x8*)&LDSo[sc * 8];
    }
}

extern "C" void kernel_launch(void* const* d_in, const int* in_sizes, int n_in,
                              void* d_out, int out_size, void* d_ws, size_t ws_size,
                              hipStream_t stream) {
    (void)in_sizes; (void)n_in; (void)out_size; (void)ws_size;
    const float* x     = (const float*)d_in[0];
    const float* gw    = (const float*)d_in[1];
    const float* gb    = (const float*)d_in[2];
    const float* qkv_w = (const float*)d_in[3];
    const float* qkv_b = (const float*)d_in[4];
    const float* out_w = (const float*)d_in[5];
    const float* out_b = (const float*)d_in[6];
    float* out = (float*)d_out;
    char* ws = (char*)d_ws;

    const size_t MB = 1024 * 1024;
    f16*   qkvT   = (f16*)ws;                       // [8][1024][1024] q|k  (16 MB)
    f16*   XT     = (f16*)(ws + 16 * MB);           // blocked [8][32][1024][16] (8 MB)
    f16*   vbuf   = (f16*)(ws + 24 * MB);           // [8][512][1024]       (8 MB)
    f16*   w2T    = (f16*)(ws + 32 * MB);           // [8][1024][512]       (8 MB)
    f16*   Wq     = (f16*)(ws + 40 * MB);           // [1536][512]          (1.5 MB)
    f16*   Wo     = (f16*)(ws + 42 * MB);           // [512][512]           (0.5 MB)
    float* qkv_bs = (float*)(ws + 43 * MB);         // [1536]

    prep<<<dim3(256 + 4103), 256, 0, stream>>>(x, gw, gb, XT,
                                               qkv_w, out_w, qkv_b, Wq, Wo, qkv_bs);
    gemm_f16<false><<<dim3(768), 256, 0, stream>>>(Wq, XT, qkv_bs, (void*)qkvT, vbuf);
    attn_f16<<<dim3(512), 256, 0, stream>>>(qkvT, vbuf, w2T);
    gemm_f16<true><<<dim3(256), 256, 0, stream>>>(Wo, w2T, out_b, (void*)out, nullptr);
}